// Round 14
// baseline (130.367 us; speedup 1.0000x reference)
//
#include <hip/hip_runtime.h>
#include <hip/hip_bf16.h>

// ProductLayer: B=4096, F=32, D=64, U=256
// out[:,   0:256] = lz       = E[B,2048] @ W1[2048,256]
// out[:, 256:512] = lp_inner = G[B,1024] @ V [1024,256]   (G_b = E_b E_b^T gram)
// out[:, 512:768] = lp_outer = M[B,4096] @ W2[4096,256]   (M rank-1 from FST, in-register)
// A = [E | G] bf16 [4096, 3072]; FST bf16 [32][64][128]; Wt bf16 [256, 7168] (N-major)
// v14: BK=32 for residency. BM=128 BN=128 BK=32, 4 waves of 64x64 (16 MFMA per
// 8 ds_read_b128), 32 KB LDS dbuf -> 5 blocks/CU capacity, 896 uniform blocks
// (512-chunks, nk=16) all resident. 4-octet swizzle oct^=(row&3)^((row>>2)&3).
// Depth-2 counted vmcnt, setprio, XCD-bijective decode, atomic epilogue.

#define KA 3072
#define KW 7168

typedef __attribute__((ext_vector_type(8))) short short8v;
typedef __attribute__((ext_vector_type(4))) float f32x4;

#define GLOAD(src, dst) __builtin_amdgcn_global_load_lds( \
    (const __attribute__((address_space(1))) void*)(src), \
    (__attribute__((address_space(3))) void*)(dst), 16, 0, 0)

static __device__ __forceinline__ short f2bf(float f) {
    union { float f; unsigned u; } v; v.f = f;
    unsigned r = v.u + 0x7fffu + ((v.u >> 16) & 1u);  // RNE
    return (short)(r >> 16);
}
static __device__ __forceinline__ float bf2f(short s) {
    union { unsigned u; float f; } v; v.u = ((unsigned)(unsigned short)s) << 16;
    return v.f;
}
static __device__ __forceinline__ int cvtpk(float lo, float hi) {
    int r;
    asm("v_cvt_pk_bf16_f32 %0, %1, %2" : "=v"(r) : "v"(lo), "v"(hi));
    return r;
}

// ---------------- prep: 0-4095 prep_a rows; 4096-4351 prep_w; 4352-5375 zero out ----
__global__ __launch_bounds__(256) void prep(const float* __restrict__ embeds,
                                            const float* __restrict__ lw,
                                            const float* __restrict__ iw,
                                            const float* __restrict__ ow,
                                            short* __restrict__ A,
                                            short* __restrict__ FST,
                                            short* __restrict__ Wt,
                                            float4* __restrict__ outv) {
    __shared__ float se[2048];
    __shared__ short sebf[2048];
    int t = threadIdx.x;

    if (blockIdx.x >= 4352) {
        size_t i = (size_t)(blockIdx.x - 4352) * 256 + t;
        #pragma unroll
        for (int r = 0; r < 3; ++r)
            outv[i + (size_t)r * 262144] = (float4){0.f, 0.f, 0.f, 0.f};
        return;
    }

    if (blockIdx.x < 4096) {
        int b = blockIdx.x;
        const float* e = embeds + (size_t)b * 2048;
        short* arow = A + (size_t)b * KA;

        float4 v0 = ((const float4*)e)[t * 2];
        float4 v1 = ((const float4*)e)[t * 2 + 1];
        ((float4*)se)[t * 2] = v0;
        ((float4*)se)[t * 2 + 1] = v1;
        short8v sb;
        sb[0] = f2bf(v0.x); sb[1] = f2bf(v0.y); sb[2] = f2bf(v0.z); sb[3] = f2bf(v0.w);
        sb[4] = f2bf(v1.x); sb[5] = f2bf(v1.y); sb[6] = f2bf(v1.z); sb[7] = f2bf(v1.w);
        ((short8v*)sebf)[t] = sb;
        *(short8v*)&arow[t * 8] = sb;   // E segment [0, 2048)

        __syncthreads();
        if (t < 64) {
            float s = 0.f;
            #pragma unroll
            for (int f = 0; f < 32; ++f) s += se[f * 64 + t];
            // transposed: FST[group b>>7][i = t][row-in-group b&127]
            FST[((size_t)(b >> 7)) * 8192 + t * 128 + (b & 127)] = f2bf(s);
        }

        // G = E E^T via MFMA: 4 waves, one 16x16 tile each, K=64 in 2 steps
        int wid = t >> 6, lane = t & 63;
        int tm = wid >> 1, tn = wid & 1;
        int lr = lane & 15, lk = (lane >> 4) * 8;
        f32x4 g = {0.f, 0.f, 0.f, 0.f};
        #pragma unroll
        for (int ks = 0; ks < 2; ++ks) {
            short8v a  = *(const short8v*)&sebf[(tm * 16 + lr) * 64 + ks * 32 + lk];
            short8v bb = *(const short8v*)&sebf[(tn * 16 + lr) * 64 + ks * 32 + lk];
            g = __builtin_amdgcn_mfma_f32_16x16x32_bf16(a, bb, g, 0, 0, 0);
        }
        #pragma unroll
        for (int r = 0; r < 4; ++r) {
            int grow = tm * 16 + (lane >> 4) * 4 + r;
            int gcol = tn * 16 + lr;
            arow[2048 + grow * 32 + gcol] = f2bf(g[r]);  // G segment [2048, 3072)
        }
    } else {
        int u = blockIdx.x - 4096;
        short* w = Wt + (size_t)u * KW;

        for (int k = t; k < 2048; k += 256) w[k] = f2bf(lw[(size_t)k * 256 + u]);

        if (t < 32) se[t] = iw[u * 32 + t];
        __syncthreads();
        for (int idx = t; idx < 1024; idx += 256)
            w[2048 + idx] = f2bf(se[idx >> 5] * se[idx & 31]);

        const float* owu = ow + (size_t)u * 4096;
        for (int i = t; i < 512; i += 256) {
            float4 a = ((const float4*)owu)[i * 2];
            float4 b = ((const float4*)owu)[i * 2 + 1];
            short8v s;
            s[0] = f2bf(a.x); s[1] = f2bf(a.y); s[2] = f2bf(a.z); s[3] = f2bf(a.w);
            s[4] = f2bf(b.x); s[5] = f2bf(b.y); s[6] = f2bf(b.z); s[7] = f2bf(b.w);
            *(short8v*)&w[3072 + i * 8] = s;
        }
    }
}

// ---------------- GEMM v14: 896 blocks x 4 waves (64x64), BM=BN=128, BK=32 ----------------
// id: xcd=id&7, s=id>>3 (0..111); mt = xcd*4+(s&3); r=s>>2 (0..27); nt=r&1; c=r>>1 (0..13).
// c 0-3: seg0 kc=c; c 4-5: seg1 kc=c-4; c 6-13: seg2 kc=c-6. All K-chunks 512, nk=16.
__global__ __launch_bounds__(256, 5) void gemm_tile(const short* __restrict__ A,
                                                    const short* __restrict__ Wt,
                                                    const short* __restrict__ FST,
                                                    float* __restrict__ out) {
    __shared__ short As[8192];    // 2 x [128 rows][32 k] bufs (seg2: whole 16KB = FST [64][128])
    __shared__ short Bs[8192];    // 2 x [128 cols][32 k] bufs

    int id = blockIdx.x;
    int xcd = id & 7, s = id >> 3;
    int mt = xcd * 4 + (s & 3);
    int r5 = s >> 2;
    int nt = r5 & 1, c = r5 >> 1;
    int seg, kc;
    if (c < 4)      { seg = 0; kc = c; }
    else if (c < 6) { seg = 1; kc = c - 4; }
    else            { seg = 2; kc = c - 6; }
    const int nk = 16;
    int brow = mt * 128, bcol = nt * 128;
    int akoff = (seg == 0) ? kc * 512 : 2048 + kc * 512;
    int boff  = (seg == 0) ? kc * 512 : (seg == 1) ? 2048 + kc * 512 : 3072 + kc * 512;

    int t = threadIdx.x, w = t >> 6, lane = t & 63;
    int wm = w >> 1, wn = w & 1;             // wave tile: rows [wm*64,+64) x cols [wn*64,+64)
    int lr = lane & 15, hi = lane >> 4;
    int srow = t >> 2;                       // staging row 0..63 per issue-round
    int soct = (t & 3) ^ ((t >> 2) & 3) ^ ((t >> 4) & 3);  // pre-swizzled source octet

    const short* Asrc = A  + (size_t)(brow + srow) * KA + akoff + soct * 8;
    const short* Bsrc = Wt + (size_t)(bcol + srow) * KW + boff  + soct * 8;
    const short* Fsrc = FST + (size_t)mt * 8192;   // linear tile, no swizzle

    auto stageA = [&](int p, int kt) {
        #pragma unroll
        for (int i = 0; i < 2; ++i)
            GLOAD(Asrc + (size_t)i * 64 * KA + kt * 32, &As[p * 4096 + i * 2048 + t * 8]);
    };
    auto stageB = [&](int p, int kt) {
        #pragma unroll
        for (int i = 0; i < 2; ++i)
            GLOAD(Bsrc + (size_t)i * 64 * KW + kt * 32, &Bs[p * 4096 + i * 2048 + t * 8]);
    };

    f32x4 acc[4][4];
    #pragma unroll
    for (int m = 0; m < 4; ++m)
        #pragma unroll
        for (int n = 0; n < 4; ++n) acc[m][n] = (f32x4){0.f, 0.f, 0.f, 0.f};

    // read octet: LDS[row][o] holds global octet o^g(row), g(row)=(row&3)^((row>>2)&3);
    // per-lane g = (lr&3)^((lr>>2)&3) (m,wm contribute 0 mod 4)
    int roct = (hi ^ (lr & 3) ^ ((lr >> 2) & 3)) * 8;

    auto compute = [&](int p) {
        short8v a[4], b[4];
        #pragma unroll
        for (int m = 0; m < 4; ++m)
            a[m] = *(const short8v*)&As[p * 4096 + (wm * 64 + m * 16 + lr) * 32 + roct];
        #pragma unroll
        for (int n = 0; n < 4; ++n)
            b[n] = *(const short8v*)&Bs[p * 4096 + (wn * 64 + n * 16 + lr) * 32 + roct];
        __builtin_amdgcn_s_setprio(1);
        #pragma unroll
        for (int m = 0; m < 4; ++m)
            #pragma unroll
            for (int n = 0; n < 4; ++n)
                acc[m][n] = __builtin_amdgcn_mfma_f32_16x16x32_bf16(a[m], b[n], acc[m][n], 0, 0, 0);
        __builtin_amdgcn_s_setprio(0);
    };

    if (seg != 2) {
        stageA(0, 0); stageB(0, 0);
        stageA(1, 1); stageB(1, 1);            // 8 vm-ops in flight
        __builtin_amdgcn_sched_barrier(0);
        for (int kt = 0; kt < nk; ++kt) {
            int cur = kt & 1;
            if (kt + 1 < nk) asm volatile("s_waitcnt vmcnt(4)" ::: "memory");
            else             asm volatile("s_waitcnt vmcnt(0)" ::: "memory");
            __builtin_amdgcn_s_barrier();          // all waves' stage-kt landed
            __builtin_amdgcn_sched_barrier(0);
            compute(cur);
            __builtin_amdgcn_sched_barrier(0);
            __builtin_amdgcn_s_barrier();          // all waves done reading buf cur
            if (kt + 2 < nk) { stageA(cur, kt + 2); stageB(cur, kt + 2); }
            __builtin_amdgcn_sched_barrier(0);
        }
    } else {
        #pragma unroll
        for (int i = 0; i < 4; ++i)              // FST tile [64 j][128 row] -> As, 16KB, linear
            GLOAD(Fsrc + i * 2048 + t * 8, &As[i * 2048 + t * 8]);
        stageB(0, 0); stageB(1, 1);              // 4 + 4 vm-ops
        asm volatile("s_waitcnt vmcnt(4)" ::: "memory");   // FST landed, B0/B1 outstanding
        __builtin_amdgcn_s_barrier();
        __builtin_amdgcn_sched_barrier(0);

        // fj[m][jh][e] = fs[row_m][jh*32 + hi*8 + e] from transposed tile (conflict-free)
        float fj[4][2][8];
        #pragma unroll
        for (int m = 0; m < 4; ++m) {
            int row = wm * 64 + m * 16 + lr;
            #pragma unroll
            for (int jh = 0; jh < 2; ++jh) {
                int j0 = jh * 32 + hi * 8;
                #pragma unroll
                for (int e = 0; e < 8; ++e)
                    fj[m][jh][e] = bf2f(As[(j0 + e) * 128 + row]);
            }
        }
        for (int kt = 0; kt < nk; ++kt) {
            int cur = kt & 1;
            if (kt + 1 < nk) asm volatile("s_waitcnt vmcnt(2)" ::: "memory");
            else             asm volatile("s_waitcnt vmcnt(0)" ::: "memory");
            __builtin_amdgcn_s_barrier();
            __builtin_amdgcn_sched_barrier(0);
            int iidx = kc * 8 + (kt >> 1);       // rank-1 column index 0..63
            int jh = kt & 1;
            float sv[4];
            #pragma unroll
            for (int m = 0; m < 4; ++m)
                sv[m] = bf2f(As[iidx * 128 + wm * 64 + m * 16 + lr]);
            short8v b[4];
            #pragma unroll
            for (int n = 0; n < 4; ++n)
                b[n] = *(const short8v*)&Bs[cur * 4096 + (wn * 64 + n * 16 + lr) * 32 + roct];
            #pragma unroll
            for (int m = 0; m < 4; ++m) {
                union { int i32[4]; short8v v; } fa;
                #pragma unroll
                for (int q2 = 0; q2 < 4; ++q2)
                    fa.i32[q2] = cvtpk(sv[m] * fj[m][jh][2 * q2], sv[m] * fj[m][jh][2 * q2 + 1]);
                __builtin_amdgcn_s_setprio(1);
                #pragma unroll
                for (int n = 0; n < 4; ++n)
                    acc[m][n] = __builtin_amdgcn_mfma_f32_16x16x32_bf16(fa.v, b[n], acc[m][n], 0, 0, 0);
                __builtin_amdgcn_s_setprio(0);
            }
            __builtin_amdgcn_sched_barrier(0);
            __builtin_amdgcn_s_barrier();          // all waves done with Bs[cur]
            if (kt + 2 < nk) stageB(cur, kt + 2);
            __builtin_amdgcn_sched_barrier(0);
        }
    }

    int segbase = seg * 256;
    #pragma unroll
    for (int m = 0; m < 4; ++m) {
        int row0 = brow + wm * 64 + m * 16 + hi * 4;
        #pragma unroll
        for (int n = 0; n < 4; ++n) {
            int col = segbase + bcol + wn * 64 + n * 16 + lr;
            #pragma unroll
            for (int r = 0; r < 4; ++r)
                unsafeAtomicAdd(&out[(size_t)(row0 + r) * 768 + col], acc[m][n][r]);
        }
    }
}

extern "C" void kernel_launch(void* const* d_in, const int* in_sizes, int n_in,
                              void* d_out, int out_size, void* d_ws, size_t ws_size,
                              hipStream_t stream) {
    const float* embeds = (const float*)d_in[0];
    const float* lw = (const float*)d_in[1];
    const float* iw = (const float*)d_in[2];
    const float* ow = (const float*)d_in[3];
    float* out = (float*)d_out;

    short* A   = (short*)d_ws;                    // 4096*3072*2 = 25,165,824 B
    short* Wt  = A + (size_t)4096 * KA;           // + 256*7168*2 = 3,670,016 B
    short* FST = Wt + (size_t)256 * KW;           // + 32*64*128*2 =   524,288 B

    prep<<<dim3(5376), dim3(256), 0, stream>>>(embeds, lw, iw, ow, A, FST, Wt, (float4*)out);
    gemm_tile<<<dim3(896), dim3(256), 0, stream>>>(A, Wt, FST, out);
}

// Round 15
// 108.183 us; speedup vs baseline: 1.2051x; 1.2051x over previous
//
#include <hip/hip_runtime.h>
#include <hip/hip_bf16.h>

// ProductLayer: B=4096, F=32, D=64, U=256
// out[:,   0:256] = lz       = E[B,2048] @ W1[2048,256]
// out[:, 256:512] = lp_inner = G[B,1024] @ V [1024,256]   (G_b = E_b E_b^T gram)
// out[:, 512:768] = lp_outer = M[B,4096] @ W2[4096,256]   (M rank-1 from FST, in-register)
// A = [E | G] bf16 [4096, 3072]; FST bf16 [32][64][128]; Wt bf16 [256, 7168] (N-major)
// v15 = v14 with the register budget FIXED: launch_bounds(256,2) (v14's (256,5)
// forced VGPR=48 -> scratch spills -> 137/140 MB spill traffic). BK=32, BM=BN=128,
// 4 waves of 64x64, 32 KB LDS dbuf (~5 blocks/CU capacity), 896 uniform blocks
// (512-chunks, nk=16) ALL resident in one generation. 4-octet swizzle, depth-2
// counted vmcnt, setprio, XCD-bijective decode, atomic epilogue.

#define KA 3072
#define KW 7168

typedef __attribute__((ext_vector_type(8))) short short8v;
typedef __attribute__((ext_vector_type(4))) float f32x4;

#define GLOAD(src, dst) __builtin_amdgcn_global_load_lds( \
    (const __attribute__((address_space(1))) void*)(src), \
    (__attribute__((address_space(3))) void*)(dst), 16, 0, 0)

static __device__ __forceinline__ short f2bf(float f) {
    union { float f; unsigned u; } v; v.f = f;
    unsigned r = v.u + 0x7fffu + ((v.u >> 16) & 1u);  // RNE
    return (short)(r >> 16);
}
static __device__ __forceinline__ float bf2f(short s) {
    union { unsigned u; float f; } v; v.u = ((unsigned)(unsigned short)s) << 16;
    return v.f;
}
static __device__ __forceinline__ int cvtpk(float lo, float hi) {
    int r;
    asm("v_cvt_pk_bf16_f32 %0, %1, %2" : "=v"(r) : "v"(lo), "v"(hi));
    return r;
}

// ---------------- prep: 0-4095 prep_a rows; 4096-4351 prep_w; 4352-5375 zero out ----
__global__ __launch_bounds__(256) void prep(const float* __restrict__ embeds,
                                            const float* __restrict__ lw,
                                            const float* __restrict__ iw,
                                            const float* __restrict__ ow,
                                            short* __restrict__ A,
                                            short* __restrict__ FST,
                                            short* __restrict__ Wt,
                                            float4* __restrict__ outv) {
    __shared__ float se[2048];
    __shared__ short sebf[2048];
    int t = threadIdx.x;

    if (blockIdx.x >= 4352) {
        size_t i = (size_t)(blockIdx.x - 4352) * 256 + t;
        #pragma unroll
        for (int r = 0; r < 3; ++r)
            outv[i + (size_t)r * 262144] = (float4){0.f, 0.f, 0.f, 0.f};
        return;
    }

    if (blockIdx.x < 4096) {
        int b = blockIdx.x;
        const float* e = embeds + (size_t)b * 2048;
        short* arow = A + (size_t)b * KA;

        float4 v0 = ((const float4*)e)[t * 2];
        float4 v1 = ((const float4*)e)[t * 2 + 1];
        ((float4*)se)[t * 2] = v0;
        ((float4*)se)[t * 2 + 1] = v1;
        short8v sb;
        sb[0] = f2bf(v0.x); sb[1] = f2bf(v0.y); sb[2] = f2bf(v0.z); sb[3] = f2bf(v0.w);
        sb[4] = f2bf(v1.x); sb[5] = f2bf(v1.y); sb[6] = f2bf(v1.z); sb[7] = f2bf(v1.w);
        ((short8v*)sebf)[t] = sb;
        *(short8v*)&arow[t * 8] = sb;   // E segment [0, 2048)

        __syncthreads();
        if (t < 64) {
            float s = 0.f;
            #pragma unroll
            for (int f = 0; f < 32; ++f) s += se[f * 64 + t];
            // transposed: FST[group b>>7][i = t][row-in-group b&127]
            FST[((size_t)(b >> 7)) * 8192 + t * 128 + (b & 127)] = f2bf(s);
        }

        // G = E E^T via MFMA: 4 waves, one 16x16 tile each, K=64 in 2 steps
        int wid = t >> 6, lane = t & 63;
        int tm = wid >> 1, tn = wid & 1;
        int lr = lane & 15, lk = (lane >> 4) * 8;
        f32x4 g = {0.f, 0.f, 0.f, 0.f};
        #pragma unroll
        for (int ks = 0; ks < 2; ++ks) {
            short8v a  = *(const short8v*)&sebf[(tm * 16 + lr) * 64 + ks * 32 + lk];
            short8v bb = *(const short8v*)&sebf[(tn * 16 + lr) * 64 + ks * 32 + lk];
            g = __builtin_amdgcn_mfma_f32_16x16x32_bf16(a, bb, g, 0, 0, 0);
        }
        #pragma unroll
        for (int r = 0; r < 4; ++r) {
            int grow = tm * 16 + (lane >> 4) * 4 + r;
            int gcol = tn * 16 + lr;
            arow[2048 + grow * 32 + gcol] = f2bf(g[r]);  // G segment [2048, 3072)
        }
    } else {
        int u = blockIdx.x - 4096;
        short* w = Wt + (size_t)u * KW;

        for (int k = t; k < 2048; k += 256) w[k] = f2bf(lw[(size_t)k * 256 + u]);

        if (t < 32) se[t] = iw[u * 32 + t];
        __syncthreads();
        for (int idx = t; idx < 1024; idx += 256)
            w[2048 + idx] = f2bf(se[idx >> 5] * se[idx & 31]);

        const float* owu = ow + (size_t)u * 4096;
        for (int i = t; i < 512; i += 256) {
            float4 a = ((const float4*)owu)[i * 2];
            float4 b = ((const float4*)owu)[i * 2 + 1];
            short8v s;
            s[0] = f2bf(a.x); s[1] = f2bf(a.y); s[2] = f2bf(a.z); s[3] = f2bf(a.w);
            s[4] = f2bf(b.x); s[5] = f2bf(b.y); s[6] = f2bf(b.z); s[7] = f2bf(b.w);
            *(short8v*)&w[3072 + i * 8] = s;
        }
    }
}

// ---------------- GEMM v15: 896 blocks x 4 waves (64x64), BM=BN=128, BK=32 ----------------
// id: xcd=id&7, s=id>>3 (0..111); mt = xcd*4+(s&3); r=s>>2 (0..27); nt=r&1; c=r>>1 (0..13).
// c 0-3: seg0 kc=c; c 4-5: seg1 kc=c-4; c 6-13: seg2 kc=c-6. All K-chunks 512, nk=16.
__global__ __launch_bounds__(256, 2) void gemm_tile(const short* __restrict__ A,
                                                    const short* __restrict__ Wt,
                                                    const short* __restrict__ FST,
                                                    float* __restrict__ out) {
    __shared__ short As[8192];    // 2 x [128 rows][32 k] bufs (seg2: whole 16KB = FST [64][128])
    __shared__ short Bs[8192];    // 2 x [128 cols][32 k] bufs

    int id = blockIdx.x;
    int xcd = id & 7, s = id >> 3;
    int mt = xcd * 4 + (s & 3);
    int r5 = s >> 2;
    int nt = r5 & 1, c = r5 >> 1;
    int seg, kc;
    if (c < 4)      { seg = 0; kc = c; }
    else if (c < 6) { seg = 1; kc = c - 4; }
    else            { seg = 2; kc = c - 6; }
    const int nk = 16;
    int brow = mt * 128, bcol = nt * 128;
    int akoff = (seg == 0) ? kc * 512 : 2048 + kc * 512;
    int boff  = (seg == 0) ? kc * 512 : (seg == 1) ? 2048 + kc * 512 : 3072 + kc * 512;

    int t = threadIdx.x, w = t >> 6, lane = t & 63;
    int wm = w >> 1, wn = w & 1;             // wave tile: rows [wm*64,+64) x cols [wn*64,+64)
    int lr = lane & 15, hi = lane >> 4;
    int srow = t >> 2;                       // staging row 0..63 per issue-round
    int soct = (t & 3) ^ ((t >> 2) & 3) ^ ((t >> 4) & 3);  // pre-swizzled source octet

    const short* Asrc = A  + (size_t)(brow + srow) * KA + akoff + soct * 8;
    const short* Bsrc = Wt + (size_t)(bcol + srow) * KW + boff  + soct * 8;
    const short* Fsrc = FST + (size_t)mt * 8192;   // linear tile, no swizzle

    auto stageA = [&](int p, int kt) {
        #pragma unroll
        for (int i = 0; i < 2; ++i)
            GLOAD(Asrc + (size_t)i * 64 * KA + kt * 32, &As[p * 4096 + i * 2048 + t * 8]);
    };
    auto stageB = [&](int p, int kt) {
        #pragma unroll
        for (int i = 0; i < 2; ++i)
            GLOAD(Bsrc + (size_t)i * 64 * KW + kt * 32, &Bs[p * 4096 + i * 2048 + t * 8]);
    };

    f32x4 acc[4][4];
    #pragma unroll
    for (int m = 0; m < 4; ++m)
        #pragma unroll
        for (int n = 0; n < 4; ++n) acc[m][n] = (f32x4){0.f, 0.f, 0.f, 0.f};

    // read octet: LDS[row][o] holds global octet o^g(row), g(row)=(row&3)^((row>>2)&3);
    // per-lane g = (lr&3)^((lr>>2)&3) (m,wm contribute 0 mod 4)
    int roct = (hi ^ (lr & 3) ^ ((lr >> 2) & 3)) * 8;

    auto compute = [&](int p) {
        short8v a[4], b[4];
        #pragma unroll
        for (int m = 0; m < 4; ++m)
            a[m] = *(const short8v*)&As[p * 4096 + (wm * 64 + m * 16 + lr) * 32 + roct];
        #pragma unroll
        for (int n = 0; n < 4; ++n)
            b[n] = *(const short8v*)&Bs[p * 4096 + (wn * 64 + n * 16 + lr) * 32 + roct];
        __builtin_amdgcn_s_setprio(1);
        #pragma unroll
        for (int m = 0; m < 4; ++m)
            #pragma unroll
            for (int n = 0; n < 4; ++n)
                acc[m][n] = __builtin_amdgcn_mfma_f32_16x16x32_bf16(a[m], b[n], acc[m][n], 0, 0, 0);
        __builtin_amdgcn_s_setprio(0);
    };

    if (seg != 2) {
        stageA(0, 0); stageB(0, 0);
        stageA(1, 1); stageB(1, 1);            // 8 vm-ops in flight
        __builtin_amdgcn_sched_barrier(0);
        for (int kt = 0; kt < nk; ++kt) {
            int cur = kt & 1;
            if (kt + 1 < nk) asm volatile("s_waitcnt vmcnt(4)" ::: "memory");
            else             asm volatile("s_waitcnt vmcnt(0)" ::: "memory");
            __builtin_amdgcn_s_barrier();          // all waves' stage-kt landed
            __builtin_amdgcn_sched_barrier(0);
            compute(cur);
            __builtin_amdgcn_sched_barrier(0);
            __builtin_amdgcn_s_barrier();          // all waves done reading buf cur
            if (kt + 2 < nk) { stageA(cur, kt + 2); stageB(cur, kt + 2); }
            __builtin_amdgcn_sched_barrier(0);
        }
    } else {
        #pragma unroll
        for (int i = 0; i < 4; ++i)              // FST tile [64 j][128 row] -> As, 16KB, linear
            GLOAD(Fsrc + i * 2048 + t * 8, &As[i * 2048 + t * 8]);
        stageB(0, 0); stageB(1, 1);              // 4 + 4 vm-ops
        asm volatile("s_waitcnt vmcnt(4)" ::: "memory");   // FST landed, B0/B1 outstanding
        __builtin_amdgcn_s_barrier();
        __builtin_amdgcn_sched_barrier(0);

        // fj[m][jh][e] = fs[row_m][jh*32 + hi*8 + e] from transposed tile (conflict-free)
        float fj[4][2][8];
        #pragma unroll
        for (int m = 0; m < 4; ++m) {
            int row = wm * 64 + m * 16 + lr;
            #pragma unroll
            for (int jh = 0; jh < 2; ++jh) {
                int j0 = jh * 32 + hi * 8;
                #pragma unroll
                for (int e = 0; e < 8; ++e)
                    fj[m][jh][e] = bf2f(As[(j0 + e) * 128 + row]);
            }
        }
        for (int kt = 0; kt < nk; ++kt) {
            int cur = kt & 1;
            if (kt + 1 < nk) asm volatile("s_waitcnt vmcnt(2)" ::: "memory");
            else             asm volatile("s_waitcnt vmcnt(0)" ::: "memory");
            __builtin_amdgcn_s_barrier();
            __builtin_amdgcn_sched_barrier(0);
            int iidx = kc * 8 + (kt >> 1);       // rank-1 column index 0..63
            int jh = kt & 1;
            float sv[4];
            #pragma unroll
            for (int m = 0; m < 4; ++m)
                sv[m] = bf2f(As[iidx * 128 + wm * 64 + m * 16 + lr]);
            short8v b[4];
            #pragma unroll
            for (int n = 0; n < 4; ++n)
                b[n] = *(const short8v*)&Bs[cur * 4096 + (wn * 64 + n * 16 + lr) * 32 + roct];
            #pragma unroll
            for (int m = 0; m < 4; ++m) {
                union { int i32[4]; short8v v; } fa;
                #pragma unroll
                for (int q2 = 0; q2 < 4; ++q2)
                    fa.i32[q2] = cvtpk(sv[m] * fj[m][jh][2 * q2], sv[m] * fj[m][jh][2 * q2 + 1]);
                __builtin_amdgcn_s_setprio(1);
                #pragma unroll
                for (int n = 0; n < 4; ++n)
                    acc[m][n] = __builtin_amdgcn_mfma_f32_16x16x32_bf16(fa.v, b[n], acc[m][n], 0, 0, 0);
                __builtin_amdgcn_s_setprio(0);
            }
            __builtin_amdgcn_sched_barrier(0);
            __builtin_amdgcn_s_barrier();          // all waves done with Bs[cur]
            if (kt + 2 < nk) stageB(cur, kt + 2);
            __builtin_amdgcn_sched_barrier(0);
        }
    }

    int segbase = seg * 256;
    #pragma unroll
    for (int m = 0; m < 4; ++m) {
        int row0 = brow + wm * 64 + m * 16 + hi * 4;
        #pragma unroll
        for (int n = 0; n < 4; ++n) {
            int col = segbase + bcol + wn * 64 + n * 16 + lr;
            #pragma unroll
            for (int r = 0; r < 4; ++r)
                unsafeAtomicAdd(&out[(size_t)(row0 + r) * 768 + col], acc[m][n][r]);
        }
    }
}

extern "C" void kernel_launch(void* const* d_in, const int* in_sizes, int n_in,
                              void* d_out, int out_size, void* d_ws, size_t ws_size,
                              hipStream_t stream) {
    const float* embeds = (const float*)d_in[0];
    const float* lw = (const float*)d_in[1];
    const float* iw = (const float*)d_in[2];
    const float* ow = (const float*)d_in[3];
    float* out = (float*)d_out;

    short* A   = (short*)d_ws;                    // 4096*3072*2 = 25,165,824 B
    short* Wt  = A + (size_t)4096 * KA;           // + 256*7168*2 = 3,670,016 B
    short* FST = Wt + (size_t)256 * KW;           // + 32*64*128*2 =   524,288 B

    prep<<<dim3(5376), dim3(256), 0, stream>>>(embeds, lw, iw, ow, A, FST, Wt, (float4*)out);
    gemm_tile<<<dim3(896), dim3(256), 0, stream>>>(A, Wt, FST, out);
}

// Round 16
// 56.332 us; speedup vs baseline: 2.3143x; 1.9205x over previous
//
#include <hip/hip_runtime.h>
#include <hip/hip_bf16.h>

// ProductLayer: B=4096, F=32, D=64, U=256
// out[:,   0:256] = lz       = E[B,2048] @ W1[2048,256]
// out[:, 256:512] = lp_inner = G[B,1024] @ V [1024,256]   (G_b = E_b E_b^T gram)
// out[:, 512:768] = lp_outer = M[B,4096] @ W2[4096,256]   (M rank-1 from FST, in-register)
// A = [E | G] bf16 [4096, 3072]; FST bf16 [32][64][128]; Wt bf16 [256, 7168] (N-major)
// v16: v10's proven block (BM=128 BN=64 BK=64, 32x64 waves, 8-oct swizzle, depth-2
// counted vmcnt, setprio) with atomic-minimizing grid: seg0/seg1 FULL-K plain-store
// blocks (nk 32/16), seg2 4-way split-K atomic (nk 16). 768 blocks = 3/CU, 48 KB
// LDS = 3-block capacity -> single resident generation. Zero only seg2 cols.

#define KA 3072
#define KW 7168

typedef __attribute__((ext_vector_type(8))) short short8v;
typedef __attribute__((ext_vector_type(4))) float f32x4;

#define GLOAD(src, dst) __builtin_amdgcn_global_load_lds( \
    (const __attribute__((address_space(1))) void*)(src), \
    (__attribute__((address_space(3))) void*)(dst), 16, 0, 0)

static __device__ __forceinline__ short f2bf(float f) {
    union { float f; unsigned u; } v; v.f = f;
    unsigned r = v.u + 0x7fffu + ((v.u >> 16) & 1u);  // RNE
    return (short)(r >> 16);
}
static __device__ __forceinline__ float bf2f(short s) {
    union { unsigned u; float f; } v; v.u = ((unsigned)(unsigned short)s) << 16;
    return v.f;
}
static __device__ __forceinline__ int cvtpk(float lo, float hi) {
    int r;
    asm("v_cvt_pk_bf16_f32 %0, %1, %2" : "=v"(r) : "v"(lo), "v"(hi));
    return r;
}

// ---- prep: 0-4095 prep_a rows; 4096-4351 prep_w; 4352-5375 zero seg2 out cols ----
__global__ __launch_bounds__(256) void prep(const float* __restrict__ embeds,
                                            const float* __restrict__ lw,
                                            const float* __restrict__ iw,
                                            const float* __restrict__ ow,
                                            short* __restrict__ A,
                                            short* __restrict__ FST,
                                            short* __restrict__ Wt,
                                            float4* __restrict__ outv) {
    __shared__ float se[2048];
    __shared__ short sebf[2048];
    int t = threadIdx.x;

    if (blockIdx.x >= 4352) {
        // zero cols [512,768) of out: 4096 rows x 64 float4/row = 262144 float4
        int idx = (blockIdx.x - 4352) * 256 + t;
        int row = idx >> 6, c4 = idx & 63;
        outv[(size_t)row * 192 + 128 + c4] = (float4){0.f, 0.f, 0.f, 0.f};
        return;
    }

    if (blockIdx.x < 4096) {
        int b = blockIdx.x;
        const float* e = embeds + (size_t)b * 2048;
        short* arow = A + (size_t)b * KA;

        float4 v0 = ((const float4*)e)[t * 2];
        float4 v1 = ((const float4*)e)[t * 2 + 1];
        ((float4*)se)[t * 2] = v0;
        ((float4*)se)[t * 2 + 1] = v1;
        short8v sb;
        sb[0] = f2bf(v0.x); sb[1] = f2bf(v0.y); sb[2] = f2bf(v0.z); sb[3] = f2bf(v0.w);
        sb[4] = f2bf(v1.x); sb[5] = f2bf(v1.y); sb[6] = f2bf(v1.z); sb[7] = f2bf(v1.w);
        ((short8v*)sebf)[t] = sb;
        *(short8v*)&arow[t * 8] = sb;   // E segment [0, 2048)

        __syncthreads();
        if (t < 64) {
            float s = 0.f;
            #pragma unroll
            for (int f = 0; f < 32; ++f) s += se[f * 64 + t];
            // transposed: FST[group b>>7][i = t][row-in-group b&127]
            FST[((size_t)(b >> 7)) * 8192 + t * 128 + (b & 127)] = f2bf(s);
        }

        // G = E E^T via MFMA: 4 waves, one 16x16 tile each, K=64 in 2 steps
        int wid = t >> 6, lane = t & 63;
        int tm = wid >> 1, tn = wid & 1;
        int lr = lane & 15, lk = (lane >> 4) * 8;
        f32x4 g = {0.f, 0.f, 0.f, 0.f};
        #pragma unroll
        for (int ks = 0; ks < 2; ++ks) {
            short8v a  = *(const short8v*)&sebf[(tm * 16 + lr) * 64 + ks * 32 + lk];
            short8v bb = *(const short8v*)&sebf[(tn * 16 + lr) * 64 + ks * 32 + lk];
            g = __builtin_amdgcn_mfma_f32_16x16x32_bf16(a, bb, g, 0, 0, 0);
        }
        #pragma unroll
        for (int r = 0; r < 4; ++r) {
            int grow = tm * 16 + (lane >> 4) * 4 + r;
            int gcol = tn * 16 + lr;
            arow[2048 + grow * 32 + gcol] = f2bf(g[r]);  // G segment [2048, 3072)
        }
    } else {
        int u = blockIdx.x - 4096;
        short* w = Wt + (size_t)u * KW;

        for (int k = t; k < 2048; k += 256) w[k] = f2bf(lw[(size_t)k * 256 + u]);

        if (t < 32) se[t] = iw[u * 32 + t];
        __syncthreads();
        for (int idx = t; idx < 1024; idx += 256)
            w[2048 + idx] = f2bf(se[idx >> 5] * se[idx & 31]);

        const float* owu = ow + (size_t)u * 4096;
        for (int i = t; i < 512; i += 256) {
            float4 a = ((const float4*)owu)[i * 2];
            float4 b = ((const float4*)owu)[i * 2 + 1];
            short8v s;
            s[0] = f2bf(a.x); s[1] = f2bf(a.y); s[2] = f2bf(a.z); s[3] = f2bf(a.w);
            s[4] = f2bf(b.x); s[5] = f2bf(b.y); s[6] = f2bf(b.z); s[7] = f2bf(b.w);
            *(short8v*)&w[3072 + i * 8] = s;
        }
    }
}

// ---- GEMM v16: 768 blocks x 4 waves (32x64), BM=128 BN=64 BK=64 ----
// xcd = id&7, s = id>>3 (0..95):
//   s 0-15:  seg0 full-K (nk=32), mtl=s&3, nt=s>>2 (0..3), plain stores
//   s 16-31: seg1 full-K (nk=16), q=s-16, mtl=q&3, nt=q>>2, plain stores
//   s 32-95: seg2 split-K4 (nk=16), q=s-32, mtl=q&3, nt=(q>>2)&3, kc=q>>4, atomic
// mt = xcd*4 + mtl.
__global__ __launch_bounds__(256) void gemm_tile(const short* __restrict__ A,
                                                 const short* __restrict__ Wt,
                                                 const short* __restrict__ FST,
                                                 float* __restrict__ out) {
    __shared__ short As[2][8192];    // 16 KB each (seg2: As[0] = FST tile [64 i][128 row])
    __shared__ short Bs[2][4096];    // 8 KB each

    int id = blockIdx.x;
    int xcd = id & 7, s = id >> 3;
    int seg, mtl, nt, kc, nk;
    if (s < 16)      { seg = 0; mtl = s & 3;  nt = s >> 2;        kc = 0;       nk = 32; }
    else if (s < 32) { int q = s - 16; seg = 1; mtl = q & 3; nt = q >> 2;       kc = 0;  nk = 16; }
    else             { int q = s - 32; seg = 2; mtl = q & 3; nt = (q >> 2) & 3; kc = q >> 4; nk = 16; }
    int mt = xcd * 4 + mtl;
    int brow = mt * 128, bcol = nt * 64;
    int akoff = (seg == 0) ? 0 : 2048;
    int boff  = (seg == 0) ? 0 : (seg == 1) ? 2048 : 3072 + kc * 1024;

    int t = threadIdx.x, w = t >> 6, lane = t & 63;
    int lr = lane & 15, hi = lane >> 4;
    int srow = t >> 3;                       // staging row 0..31 per issue
    int soct = (t & 7) ^ (srow & 7);         // pre-swizzled source octet (involution)

    const short* Asrc = A  + (size_t)(brow + srow) * KA + akoff + soct * 8;
    const short* Bsrc = Wt + (size_t)(bcol + srow) * KW + boff  + soct * 8;
    const short* Fsrc = FST + (size_t)mt * 8192;   // transposed tile, linear

    auto stageA = [&](int p, int kt) {
        #pragma unroll
        for (int i = 0; i < 4; ++i)
            GLOAD(Asrc + (size_t)i * 32 * KA + kt * 64, &As[p][i * 2048 + t * 8]);
    };
    auto stageB = [&](int p, int kt) {
        #pragma unroll
        for (int i = 0; i < 2; ++i)
            GLOAD(Bsrc + (size_t)i * 32 * KW + kt * 64, &Bs[p][i * 2048 + t * 8]);
    };

    f32x4 acc[2][4];
    #pragma unroll
    for (int m = 0; m < 2; ++m)
        #pragma unroll
        for (int n = 0; n < 4; ++n) acc[m][n] = (f32x4){0.f, 0.f, 0.f, 0.f};

    auto compute = [&](const short* a_s, const short* b_s) {
        #pragma unroll
        for (int ks = 0; ks < 2; ++ks) {
            int oct = ((ks * 4 + hi) ^ (lr & 7)) * 8;   // swizzled read octet
            short8v a[2], b[4];
            #pragma unroll
            for (int m = 0; m < 2; ++m)
                a[m] = *(const short8v*)&a_s[(w * 32 + m * 16 + lr) * 64 + oct];
            #pragma unroll
            for (int n = 0; n < 4; ++n)
                b[n] = *(const short8v*)&b_s[(n * 16 + lr) * 64 + oct];
            __builtin_amdgcn_s_setprio(1);
            #pragma unroll
            for (int m = 0; m < 2; ++m)
                #pragma unroll
                for (int n = 0; n < 4; ++n)
                    acc[m][n] = __builtin_amdgcn_mfma_f32_16x16x32_bf16(a[m], b[n], acc[m][n], 0, 0, 0);
            __builtin_amdgcn_s_setprio(0);
        }
    };

    if (seg != 2) {
        stageA(0, 0); stageB(0, 0);
        stageA(1, 1); stageB(1, 1);            // 12 vm-ops in flight
        __builtin_amdgcn_sched_barrier(0);
        for (int kt = 0; kt < nk; ++kt) {
            int cur = kt & 1;
            if (kt + 1 < nk) asm volatile("s_waitcnt vmcnt(6)" ::: "memory");
            else             asm volatile("s_waitcnt vmcnt(0)" ::: "memory");
            __builtin_amdgcn_s_barrier();          // all waves' stage-kt landed
            __builtin_amdgcn_sched_barrier(0);
            compute(As[cur], Bs[cur]);
            __builtin_amdgcn_sched_barrier(0);
            __builtin_amdgcn_s_barrier();          // all waves done reading buf cur
            if (kt + 2 < nk) { stageA(cur, kt + 2); stageB(cur, kt + 2); }
            __builtin_amdgcn_sched_barrier(0);
        }
    } else {
        #pragma unroll
        for (int i = 0; i < 4; ++i)              // FST tile [64 i][128 row] -> As[0], linear
            GLOAD(Fsrc + i * 2048 + t * 8, &As[0][i * 2048 + t * 8]);
        stageB(0, 0); stageB(1, 1);              // 4 + 4 vm-ops in flight
        asm volatile("s_waitcnt vmcnt(4)" ::: "memory");   // FST landed
        __builtin_amdgcn_s_barrier();
        __builtin_amdgcn_sched_barrier(0);

        // fj[m][ks][e] = fs[row_m][(ks*4+hi)*8+e] from transposed tile (conflict-free)
        float fj[2][2][8];
        #pragma unroll
        for (int m = 0; m < 2; ++m) {
            int row = w * 32 + m * 16 + lr;
            #pragma unroll
            for (int ks = 0; ks < 2; ++ks) {
                int j0 = (ks * 4 + hi) * 8;
                #pragma unroll
                for (int e = 0; e < 8; ++e)
                    fj[m][ks][e] = bf2f(As[0][(j0 + e) * 128 + row]);
            }
        }
        for (int kt = 0; kt < nk; ++kt) {
            int cur = kt & 1;
            if (kt + 1 < nk) asm volatile("s_waitcnt vmcnt(2)" ::: "memory");
            else             asm volatile("s_waitcnt vmcnt(0)" ::: "memory");
            __builtin_amdgcn_s_barrier();
            __builtin_amdgcn_sched_barrier(0);
            int iidx = kc * 16 + kt;             // rank-1 column index 0..63
            float sv[2];
            #pragma unroll
            for (int m = 0; m < 2; ++m)
                sv[m] = bf2f(As[0][iidx * 128 + w * 32 + m * 16 + lr]);
            #pragma unroll
            for (int ks = 0; ks < 2; ++ks) {
                int oct = ((ks * 4 + hi) ^ (lr & 7)) * 8;
                short8v b[4];
                #pragma unroll
                for (int n = 0; n < 4; ++n)
                    b[n] = *(const short8v*)&Bs[cur][(n * 16 + lr) * 64 + oct];
                #pragma unroll
                for (int m = 0; m < 2; ++m) {
                    union { int i32[4]; short8v v; } fa;
                    #pragma unroll
                    for (int q2 = 0; q2 < 4; ++q2)
                        fa.i32[q2] = cvtpk(sv[m] * fj[m][ks][2 * q2], sv[m] * fj[m][ks][2 * q2 + 1]);
                    __builtin_amdgcn_s_setprio(1);
                    #pragma unroll
                    for (int n = 0; n < 4; ++n)
                        acc[m][n] = __builtin_amdgcn_mfma_f32_16x16x32_bf16(fa.v, b[n], acc[m][n], 0, 0, 0);
                    __builtin_amdgcn_s_setprio(0);
                }
            }
            __builtin_amdgcn_sched_barrier(0);
            __builtin_amdgcn_s_barrier();          // all waves done with Bs[cur]
            if (kt + 2 < nk) stageB(cur, kt + 2);
            __builtin_amdgcn_sched_barrier(0);
        }
    }

    int segbase = seg * 256;
    if (seg != 2) {
        #pragma unroll
        for (int m = 0; m < 2; ++m) {
            int row0 = brow + w * 32 + m * 16 + hi * 4;
            #pragma unroll
            for (int n = 0; n < 4; ++n) {
                int col = segbase + bcol + n * 16 + lr;
                #pragma unroll
                for (int r = 0; r < 4; ++r)
                    out[(size_t)(row0 + r) * 768 + col] = acc[m][n][r];
            }
        }
    } else {
        #pragma unroll
        for (int m = 0; m < 2; ++m) {
            int row0 = brow + w * 32 + m * 16 + hi * 4;
            #pragma unroll
            for (int n = 0; n < 4; ++n) {
                int col = segbase + bcol + n * 16 + lr;
                #pragma unroll
                for (int r = 0; r < 4; ++r)
                    unsafeAtomicAdd(&out[(size_t)(row0 + r) * 768 + col], acc[m][n][r]);
            }
        }
    }
}

extern "C" void kernel_launch(void* const* d_in, const int* in_sizes, int n_in,
                              void* d_out, int out_size, void* d_ws, size_t ws_size,
                              hipStream_t stream) {
    const float* embeds = (const float*)d_in[0];
    const float* lw = (const float*)d_in[1];
    const float* iw = (const float*)d_in[2];
    const float* ow = (const float*)d_in[3];
    float* out = (float*)d_out;

    short* A   = (short*)d_ws;                    // 4096*3072*2 = 25,165,824 B
    short* Wt  = A + (size_t)4096 * KA;           // + 256*7168*2 = 3,670,016 B
    short* FST = Wt + (size_t)256 * KW;           // + 32*64*128*2 =   524,288 B

    prep<<<dim3(5376), dim3(256), 0, stream>>>(embeds, lw, iw, ow, A, FST, Wt, (float4*)out);
    gemm_tile<<<dim3(768), dim3(256), 0, stream>>>(A, Wt, FST, out);
}